// Round 9
// baseline (593.682 us; speedup 1.0000x reference)
//
#include <hip/hip_runtime.h>
#include <hip/hip_bf16.h>
#include <math.h>

//  x:        [N,128] f32      (in 0)
//  edge_index[2,E]   i32      (in 1)
//  edge_x:   [E,16]  f32      (in 2)
//  W1 [16,32] b1[32] W2[32,1] b2[1]   (in 3..6)
//  Wg1[128,128] bg1[128] Wg2[128,40] bg2[40]  (in 7..10)
//  out:      [N,40]  f32

#define NF   128
#define EF   16
#define EFIL 32
#define NCLS 40
#define TILE 4096   // edges per tile for pass-1 sort

// pack two fp32 -> 2xbf16 (RTNE), lo in low half
__device__ inline unsigned pack_bf16x2(float a, float b) {
    unsigned ua = __float_as_uint(a);
    unsigned ub = __float_as_uint(b);
    ua += 0x7FFF + ((ua >> 16) & 1);
    ub += 0x7FFF + ((ub >> 16) & 1);
    return (ua >> 16) | (ub & 0xFFFF0000u);
}
__device__ inline float bf16_lo(unsigned u) { return __uint_as_float(u << 16); }
__device__ inline float bf16_hi(unsigned u) { return __uint_as_float(u & 0xFFFF0000u); }

// -------------------- pass1 histogram: digit = col>>8, LDS only
__global__ __launch_bounds__(256) void hist1_kernel(
    const int* __restrict__ col, int* __restrict__ hist, int E, int ntiles)
{
    __shared__ int h[256];
    int t = threadIdx.x;
    h[t] = 0;
    __syncthreads();
    int tile = blockIdx.x;
    int base = tile * TILE;
    int end = base + TILE; if (end > E) end = E;
    for (int i = base + t; i < end; i += 256)
        atomicAdd(&h[col[i] >> 8], 1);
    __syncthreads();
    hist[t * ntiles + tile] = h[t];
}

// ---- scanA: one block per digit; exclusive scan of hist[d][0..ntiles) in
//      place (digit-major, coalesced), digit total -> dtot[d]
__global__ __launch_bounds__(256) void scanA_kernel(
    int* __restrict__ hist, int* __restrict__ dtot, int ntiles)
{
    __shared__ int ts[256];
    int d = blockIdx.x;
    int t = threadIdx.x;
    int* hrow = hist + (size_t)d * ntiles;
    int C = (ntiles + 255) >> 8;
    int b = t * C;
    int e = b + C; if (e > ntiles) e = ntiles;
    int s = 0;
    for (int i = b; i < e; i++) s += hrow[i];
    ts[t] = s;
    __syncthreads();
    for (int dd = 1; dd < 256; dd <<= 1) {
        int v = (t >= dd) ? ts[t - dd] : 0;
        __syncthreads();
        ts[t] += v;
        __syncthreads();
    }
    int run = ts[t] - s;   // exclusive prefix of this thread's chunk
    for (int i = b; i < e; i++) {
        int v = hrow[i];
        hrow[i] = run;     // in-place exclusive within-digit prefix
        run += v;
    }
    if (t == 255) dtot[d] = ts[255];
}

// ---- scanB: exclusive scan of 256 digit totals -> dbase[0..256]
__global__ __launch_bounds__(256) void scanB_kernel(
    const int* __restrict__ dtot, int* __restrict__ dbase, int E)
{
    __shared__ int ts[256];
    int t = threadIdx.x;
    int s = dtot[t];
    ts[t] = s;
    __syncthreads();
    for (int dd = 1; dd < 256; dd <<= 1) {
        int v = (t >= dd) ? ts[t - dd] : 0;
        __syncthreads();
        ts[t] += v;
        __syncthreads();
    }
    dbase[t] = ts[t] - s;
    if (t == 255) dbase[256] = E;
}

// ---- fused edge-MLP + pass1 scatter: per edge compute ew = sigmoid(MLP),
//      bucket by col>>8, ONE 8B store: (src<<8 | col&255, ew_f32)
__global__ __launch_bounds__(512) void scatter_mlp_kernel(
    const float* __restrict__ ex, const float* __restrict__ W1,
    const float* __restrict__ b1, const float* __restrict__ W2,
    const float* __restrict__ b2,
    const int* __restrict__ row, const int* __restrict__ col,
    const int* __restrict__ hscan, const int* __restrict__ dbase,
    uint2* __restrict__ st, int E, int ntiles)
{
    __shared__ float sW1[EF * EFIL];
    __shared__ float sb1[EFIL];
    __shared__ float sW2[EFIL];
    __shared__ float sb2;
    __shared__ int cur[256];
    int t = threadIdx.x;
    int tile = blockIdx.x;
    for (int i = t; i < EF * EFIL; i += 512) sW1[i] = W1[i];
    if (t < EFIL) { sb1[t] = b1[t]; sW2[t] = W2[t]; }
    if (t == 0) sb2 = b2[0];
    if (t < 256) cur[t] = dbase[t] + hscan[t * ntiles + tile];
    __syncthreads();

    int base = tile * TILE;
    int end = base + TILE; if (end > E) end = E;
    for (int i = base + t; i < end; i += 512) {
        float xv[EF];
        const float4* exv = (const float4*)(ex) + (size_t)i * (EF / 4);
        #pragma unroll
        for (int q = 0; q < EF / 4; q++) {
            float4 v = exv[q];
            xv[q * 4 + 0] = v.x; xv[q * 4 + 1] = v.y;
            xv[q * 4 + 2] = v.z; xv[q * 4 + 3] = v.w;
        }
        float acc = sb2;
        #pragma unroll
        for (int j = 0; j < EFIL; j++) {
            float h = sb1[j];
            #pragma unroll
            for (int k = 0; k < EF; k++) h += xv[k] * sW1[k * EFIL + j];
            acc += fmaxf(h, 0.0f) * sW2[j];
        }
        float s = 1.0f / (1.0f + expf(-acc));
        int c = col[i];
        int r = row[i];
        int p = atomicAdd(&cur[c >> 8], 1);
        st[p] = make_uint2(((unsigned)r << 8) | (unsigned)(c & 255),
                           __float_as_uint(s));
    }
}

// ---- pass2: per-bucket counting sort by col&255 + offs + deg/dinv (fused)
//      reads packed 8B records, writes packed 8B final records
__global__ __launch_bounds__(512) void bucket_sort_kernel(
    const uint2* __restrict__ st, const int* __restrict__ dbase,
    uint2* __restrict__ edgeF, int* __restrict__ offs, float* __restrict__ dinv,
    int E, int N)
{
    __shared__ int   cnt[256];
    __shared__ int   scan[256];
    __shared__ int   cursor[256];
    __shared__ float dsum[256];
    __shared__ float sdinv[256];
    int t = threadIdx.x;
    int b = blockIdx.x;
    if (t == 0 && b == 0) offs[N] = E;
    int bstart = dbase[b];
    int bend   = dbase[b + 1];
    if (t < 256) { cnt[t] = 0; dsum[t] = 0.0f; sdinv[t] = 0.0f; }
    __syncthreads();
    for (int i = bstart + t; i < bend; i += 512) {
        uint2 v = st[i];
        int lo = (int)(v.x & 255u);
        atomicAdd(&cnt[lo], 1);
        atomicAdd(&dsum[lo], __uint_as_float(v.y));
    }
    __syncthreads();
    if (t < 256) scan[t] = cnt[t];
    __syncthreads();
    for (int d = 1; d < 256; d <<= 1) {
        int v = 0;
        if (t < 256 && t >= d) v = scan[t - d];
        __syncthreads();
        if (t < 256) scan[t] += v;
        __syncthreads();
    }
    if (t < 256) {
        int excl = scan[t] - cnt[t];
        int c = (b << 8) + t;
        cursor[t] = bstart + excl;
        if (c < N) {
            offs[c] = bstart + excl;
            float deg = 1.0f + dsum[t];
            float di = rsqrtf(deg);
            sdinv[t] = di;
            dinv[c] = di;
        }
    }
    __syncthreads();
    for (int i = bstart + t; i < bend; i += 512) {
        uint2 v = st[i];
        int lo = (int)(v.x & 255u);
        int p = atomicAdd(&cursor[lo], 1);
        float w = __uint_as_float(v.y) * sdinv[lo];  // * dinv[col]; dinv[src] in h'
        edgeF[p] = make_uint2(v.x >> 8, __float_as_uint(w));
    }
}

// ------------------- GEMM1: h1' = (x @ Wg1) * dinv[row] -> bf16  (128->128)
#define G1_ROWS 64
#define XPAD 68
__global__ __launch_bounds__(256, 4) void gemm1_kernel(
    const float* __restrict__ x, const float* __restrict__ W,
    const float* __restrict__ dinv, unsigned short* __restrict__ h1b, int N)
{
    __shared__ float sx[NF * XPAD];        // sx[k*XPAD + r]
    int t = threadIdx.x;
    int row0 = blockIdx.x * G1_ROWS;
    for (int i = t; i < G1_ROWS * NF; i += 256) {
        int r = i >> 7, k = i & 127;
        int gr = row0 + r;
        sx[k * XPAD + r] = (gr < N) ? x[(size_t)gr * NF + k] : 0.0f;
    }
    __syncthreads();

    int fg = t & 31, rg = t >> 5;
    int f0 = fg * 4, r0 = rg * 8;
    float acc[8][4];
    #pragma unroll
    for (int r = 0; r < 8; r++)
        #pragma unroll
        for (int c = 0; c < 4; c++) acc[r][c] = 0.0f;

    #pragma unroll 8
    for (int k = 0; k < NF; k++) {
        float4 w  = *(const float4*)&W[(size_t)k * NF + f0];
        float4 xa = *(const float4*)&sx[k * XPAD + r0];
        float4 xb = *(const float4*)&sx[k * XPAD + r0 + 4];
        float xr[8] = {xa.x, xa.y, xa.z, xa.w, xb.x, xb.y, xb.z, xb.w};
        #pragma unroll
        for (int r = 0; r < 8; r++) {
            acc[r][0] += xr[r] * w.x;
            acc[r][1] += xr[r] * w.y;
            acc[r][2] += xr[r] * w.z;
            acc[r][3] += xr[r] * w.w;
        }
    }
    #pragma unroll
    for (int r = 0; r < 8; r++) {
        int gr = row0 + r0 + r;
        if (gr < N) {
            float di = dinv[gr];
            uint2 p;
            p.x = pack_bf16x2(acc[r][0] * di, acc[r][1] * di);
            p.y = pack_bf16x2(acc[r][2] * di, acc[r][3] * di);
            *(uint2*)(h1b + (size_t)gr * NF + f0) = p;
        }
    }
}

// --------------- gather1: out1[c] = bg1 + h1'[c]*di + sum_e w*h1'[src]
// one wave per node; 64 lanes x (2xbf16); inner loop unrolled x8 for MLP
__global__ __launch_bounds__(256) void gather1_kernel(
    const int* __restrict__ offs, const uint2* __restrict__ edgeF,
    const unsigned short* __restrict__ h1b,
    const float* __restrict__ dinv, const float* __restrict__ bg1,
    float* __restrict__ out1, int N)
{
    int wid  = threadIdx.x >> 6;
    int lane = threadIdx.x & 63;
    int c = blockIdx.x * 4 + wid;
    if (c >= N) return;
    float di = dinv[c];
    unsigned hu = *(const unsigned*)(h1b + (size_t)c * NF + 2 * lane);
    float2 acc;
    acc.x = bg1[2 * lane]     + bf16_lo(hu) * di;  // h1' already has one dinv
    acc.y = bg1[2 * lane + 1] + bf16_hi(hu) * di;

    int beg = offs[c], end = offs[c + 1];
    for (int e0 = beg; e0 < end; e0 += 64) {
        int idx = e0 + lane;
        uint2 eg = make_uint2(0u, 0u);
        if (idx < end) eg = edgeF[idx];
        int sv = (int)eg.x; float wv = __uint_as_float(eg.y);
        int m = end - e0; if (m > 64) m = 64;
        int j = 0;
        for (; j + 8 <= m; j += 8) {
            unsigned v[8]; float w[8];
            #pragma unroll
            for (int u = 0; u < 8; u++) {
                int s = __shfl(sv, j + u);
                w[u] = __shfl(wv, j + u);
                v[u] = *(const unsigned*)(h1b + (size_t)s * NF + 2 * lane);
            }
            #pragma unroll
            for (int u = 0; u < 8; u++) {
                acc.x += w[u] * bf16_lo(v[u]);
                acc.y += w[u] * bf16_hi(v[u]);
            }
        }
        for (; j < m; j++) {
            int   s = __shfl(sv, j);
            float w = __shfl(wv, j);
            unsigned v = *(const unsigned*)(h1b + (size_t)s * NF + 2 * lane);
            acc.x += w * bf16_lo(v);
            acc.y += w * bf16_hi(v);
        }
    }
    *(float2*)(out1 + (size_t)c * NF + 2 * lane) = acc;
}

// ----------------- GEMM2: h2' = (relu(out1) @ Wg2) * dinv[row] -> bf16
#define G2_ROWS 64
__global__ __launch_bounds__(256, 4) void gemm2_kernel(
    const float* __restrict__ out1, const float* __restrict__ W,
    const float* __restrict__ dinv, unsigned short* __restrict__ h2b, int N)
{
    __shared__ float sx[NF * XPAD];
    int t = threadIdx.x;
    int row0 = blockIdx.x * G2_ROWS;
    for (int i = t; i < G2_ROWS * NF; i += 256) {
        int r = i >> 7, k = i & 127;
        int gr = row0 + r;
        sx[k * XPAD + r] = (gr < N) ? fmaxf(out1[(size_t)gr * NF + k], 0.0f) : 0.0f;
    }
    __syncthreads();

    int fg = t & 15, rg = t >> 4;
    int f0 = fg * 4;
    int f0c = (f0 <= NCLS - 4) ? f0 : (NCLS - 4);
    int r0 = rg * 4;
    float acc[4][4];
    #pragma unroll
    for (int r = 0; r < 4; r++)
        #pragma unroll
        for (int c = 0; c < 4; c++) acc[r][c] = 0.0f;

    #pragma unroll 8
    for (int k = 0; k < NF; k++) {
        float4 w  = *(const float4*)&W[(size_t)k * NCLS + f0c];
        float4 xa = *(const float4*)&sx[k * XPAD + r0];
        float xr[4] = {xa.x, xa.y, xa.z, xa.w};
        #pragma unroll
        for (int r = 0; r < 4; r++) {
            acc[r][0] += xr[r] * w.x;
            acc[r][1] += xr[r] * w.y;
            acc[r][2] += xr[r] * w.z;
            acc[r][3] += xr[r] * w.w;
        }
    }
    if (f0 <= NCLS - 4) {
        #pragma unroll
        for (int r = 0; r < 4; r++) {
            int gr = row0 + r0 + r;
            if (gr < N) {
                float di = dinv[gr];
                uint2 p;
                p.x = pack_bf16x2(acc[r][0] * di, acc[r][1] * di);
                p.y = pack_bf16x2(acc[r][2] * di, acc[r][3] * di);
                *(uint2*)(h2b + (size_t)gr * NCLS + f0) = p;
            }
        }
    }
}

// --------------- gather2: out[c] = bg2 + h2'[c]*di + sum_e w*h2'[src]
// lanes 0..19 each handle 2 feats (2xbf16 per load)
__global__ __launch_bounds__(256) void gather2_kernel(
    const int* __restrict__ offs, const uint2* __restrict__ edgeF,
    const unsigned short* __restrict__ h2b,
    const float* __restrict__ dinv, const float* __restrict__ bg2,
    float* __restrict__ out, int N)
{
    int wid  = threadIdx.x >> 6;
    int lane = threadIdx.x & 63;
    int c = blockIdx.x * 4 + wid;
    if (c >= N) return;
    float di = dinv[c];
    float2 acc = {0.0f, 0.0f};
    if (lane < NCLS / 2) {
        unsigned hu = *(const unsigned*)(h2b + (size_t)c * NCLS + 2 * lane);
        acc.x = bg2[2 * lane]     + bf16_lo(hu) * di;
        acc.y = bg2[2 * lane + 1] + bf16_hi(hu) * di;
    }

    int beg = offs[c], end = offs[c + 1];
    for (int e0 = beg; e0 < end; e0 += 64) {
        int idx = e0 + lane;
        uint2 eg = make_uint2(0u, 0u);
        if (idx < end) eg = edgeF[idx];
        int sv = (int)eg.x; float wv = __uint_as_float(eg.y);
        int m = end - e0; if (m > 64) m = 64;
        int j = 0;
        for (; j + 8 <= m; j += 8) {
            unsigned v[8]; float w[8];
            #pragma unroll
            for (int u = 0; u < 8; u++) {
                int s = __shfl(sv, j + u);
                w[u] = __shfl(wv, j + u);
                v[u] = (lane < NCLS / 2)
                     ? *(const unsigned*)(h2b + (size_t)s * NCLS + 2 * lane) : 0u;
            }
            #pragma unroll
            for (int u = 0; u < 8; u++) {
                acc.x += w[u] * bf16_lo(v[u]);
                acc.y += w[u] * bf16_hi(v[u]);
            }
        }
        for (; j < m; j++) {
            int   s = __shfl(sv, j);
            float w = __shfl(wv, j);
            if (lane < NCLS / 2) {
                unsigned v = *(const unsigned*)(h2b + (size_t)s * NCLS + 2 * lane);
                acc.x += w * bf16_lo(v);
                acc.y += w * bf16_hi(v);
            }
        }
    }
    if (lane < NCLS / 2) *(float2*)(out + (size_t)c * NCLS + 2 * lane) = acc;
}

// ============================================================== launch
extern "C" void kernel_launch(void* const* d_in, const int* in_sizes, int n_in,
                              void* d_out, int out_size, void* d_ws, size_t ws_size,
                              hipStream_t stream)
{
    const float* x   = (const float*)d_in[0];
    const int*   ei  = (const int*)d_in[1];
    const float* exf = (const float*)d_in[2];
    const float* W1  = (const float*)d_in[3];
    const float* b1  = (const float*)d_in[4];
    const float* W2  = (const float*)d_in[5];
    const float* b2  = (const float*)d_in[6];
    const float* Wg1 = (const float*)d_in[7];
    const float* bg1 = (const float*)d_in[8];
    const float* Wg2 = (const float*)d_in[9];
    const float* bg2 = (const float*)d_in[10];
    float* out = (float*)d_out;

    int N = in_sizes[0] / NF;
    int E = in_sizes[2] / EF;
    const int* row = ei;
    const int* col = ei + E;
    int ntiles = (E + TILE - 1) / TILE;
    int L = 256 * ntiles;

    // workspace bump allocator (4-byte words)
    char* base = (char*)d_ws;
    size_t off = 0;
    auto alloc = [&](size_t words) -> void* {
        void* p = base + off * 4;
        off += (words + 3) & ~(size_t)3;
        return p;
    };
    // region A: staged uint2 records (2E words); h1b/h2b alias after consume
    size_t stwords = (size_t)2 * E;
    size_t hwords = ((size_t)N * NF + 1) / 2;   // bf16 h1 = N*128*2B
    if (hwords > stwords) stwords = hwords;
    uint2* st   = (uint2*)alloc(stwords);
    unsigned short* h1b = (unsigned short*)st;   // alias (after sort consumed)
    unsigned short* h2b = (unsigned short*)st;   // alias (after gather1 consumed)
    // region B: final CSR (packed 8B records)
    uint2* edgeF = (uint2*)alloc((size_t)2 * E);
    // region C: out1
    float* out1 = (float*)alloc((size_t)N * NF);
    // region D: small
    float* dinv = (float*)alloc(N);
    int*   offs = (int*)  alloc(N + 1);
    int*   hist = (int*)  alloc(L);
    int*   dtot = (int*)  alloc(256);
    int*   dbase= (int*)  alloc(257);

    int nb;
    hist1_kernel<<<ntiles, 256, 0, stream>>>(col, hist, E, ntiles);
    scanA_kernel<<<256, 256, 0, stream>>>(hist, dtot, ntiles);
    scanB_kernel<<<1, 256, 0, stream>>>(dtot, dbase, E);
    scatter_mlp_kernel<<<ntiles, 512, 0, stream>>>(exf, W1, b1, W2, b2,
                                                   row, col, hist, dbase,
                                                   st, E, ntiles);
    bucket_sort_kernel<<<256, 512, 0, stream>>>(st, dbase, edgeF, offs, dinv, E, N);

    nb = (N + G1_ROWS - 1) / G1_ROWS;
    gemm1_kernel<<<nb, 256, 0, stream>>>(x, Wg1, dinv, h1b, N);

    nb = (N + 3) / 4;
    gather1_kernel<<<nb, 256, 0, stream>>>(offs, edgeF, h1b, dinv, bg1, out1, N);

    nb = (N + G2_ROWS - 1) / G2_ROWS;
    gemm2_kernel<<<nb, 256, 0, stream>>>(out1, Wg2, dinv, h2b, N);

    nb = (N + 3) / 4;
    gather2_kernel<<<nb, 256, 0, stream>>>(offs, edgeF, h2b, dinv, bg2, out, N);
}